// Round 7
// baseline (677.388 us; speedup 1.0000x reference)
//
#include <hip/hip_runtime.h>

// Problem constants
#define B_  2
#define S_  1024
#define H_  16
#define DK_ 64
#define D_  1024

static const size_t BSD  = (size_t)B_ * S_ * D_;        // 2,097,152
static const size_t BHSS = (size_t)B_ * H_ * S_ * S_;   // 33,554,432

typedef __attribute__((ext_vector_type(8))) short bf16x8;
typedef __attribute__((ext_vector_type(4))) float floatx4;

__device__ __forceinline__ unsigned short f2bf(float f) {
  unsigned u = __builtin_bit_cast(unsigned, f);
  unsigned r = (u + 0x7FFFu + ((u >> 16) & 1u)) >> 16;
  return (unsigned short)r;
}

// ---------------------------------------------------------------------------
// Flat fp32 -> bf16 convert (float4 per thread)
// ---------------------------------------------------------------------------
__global__ __launch_bounds__(256) void cvt_bf16_kernel(
    const float* __restrict__ src, unsigned short* __restrict__ dst, int n4) {
  int i = (blockIdx.x << 8) + threadIdx.x;
  if (i >= n4) return;
  float4 v = ((const float4*)src)[i];
  ushort4 o;
  o.x = f2bf(v.x); o.y = f2bf(v.y); o.z = f2bf(v.z); o.w = f2bf(v.w);
  ((ushort4*)dst)[i] = o;
}

// ---------------------------------------------------------------------------
// bf16 NT GEMM (MFMA): C[n][m] = sum_k A[n][k]*Bw[m][k], A,Bw bf16 row-major.
// 64x64 tile, BK=32, 256 thr = 4 waves, wave does 32x32 (2x2 of 16x16x32).
// bf16_out: 1 -> store bf16, 0 -> store fp32 (+ optional corr[b*1024+col]).
// grid (Mcols/64, N/64)
// ---------------------------------------------------------------------------
__global__ __launch_bounds__(256) void gemm_bf16_nt_kernel(
    const unsigned short* __restrict__ A, const unsigned short* __restrict__ Bw,
    void* __restrict__ Cout, int K, int Mcols, int bf16_out,
    const float* __restrict__ corr) {
  __shared__ short As[64 * 40];
  __shared__ short Bs[64 * 40];
  int tid = threadIdx.x;
  int lane = tid & 63, w = tid >> 6;
  int quad = lane >> 4, xn = lane & 15;
  int row0 = blockIdx.y << 6, col0 = blockIdx.x << 6;
  int rw = w & 1, cw = w >> 1;
  int srow = tid >> 2, sk = (tid & 3) << 3;   // staging: row 0..63, k-chunk
  const unsigned short* Ap = A + (size_t)(row0 + srow) * K + sk;
  const unsigned short* Bp = Bw + (size_t)(col0 + srow) * K + sk;
  floatx4 acc[2][2] = {};
  for (int k0 = 0; k0 < K; k0 += 32) {
    uint4 av = *(const uint4*)(Ap + k0);
    uint4 bv = *(const uint4*)(Bp + k0);
    *(uint4*)&As[srow * 40 + sk] = av;
    *(uint4*)&Bs[srow * 40 + sk] = bv;
    __syncthreads();
    bf16x8 af[2], bf[2];
#pragma unroll
    for (int rt = 0; rt < 2; ++rt)
      af[rt] = *(const bf16x8*)&As[(rw * 32 + rt * 16 + xn) * 40 + quad * 8];
#pragma unroll
    for (int ct = 0; ct < 2; ++ct)
      bf[ct] = *(const bf16x8*)&Bs[(cw * 32 + ct * 16 + xn) * 40 + quad * 8];
#pragma unroll
    for (int rt = 0; rt < 2; ++rt)
#pragma unroll
      for (int ct = 0; ct < 2; ++ct)
        acc[rt][ct] = __builtin_amdgcn_mfma_f32_16x16x32_bf16(
            af[rt], bf[ct], acc[rt][ct], 0, 0, 0);
    __syncthreads();
  }
#pragma unroll
  for (int rt = 0; rt < 2; ++rt)
#pragma unroll
    for (int ct = 0; ct < 2; ++ct) {
      int colg = col0 + cw * 32 + ct * 16 + xn;
#pragma unroll
      for (int r = 0; r < 4; ++r) {
        int rowg = row0 + rw * 32 + rt * 16 + quad * 4 + r;
        if (bf16_out)
          ((unsigned short*)Cout)[(size_t)rowg * Mcols + colg] = f2bf(acc[rt][ct][r]);
        else {
          float v = acc[rt][ct][r];
          if (corr) v += corr[((rowg >> 10) << 10) + colg];
          ((float*)Cout)[(size_t)rowg * Mcols + colg] = v;
        }
      }
    }
}

// ---------------------------------------------------------------------------
// Scores (MFMA): M[b,h,s,t] = sum_d Q[b,s,h,d]*K[b,t,h,d], Q/K bf16 [B,S,H*DK].
// Output bf16 planar [B,H,S,S]. Tile 128 (s) x 64 (t), K=64 single stage.
// grid (S/64, S/128, B*H), 256 thr = 4 waves, wave = 32 s-rows x 64 t-cols.
// ---------------------------------------------------------------------------
__global__ __launch_bounds__(256) void scores_mfma_kernel(
    const unsigned short* __restrict__ Q, const unsigned short* __restrict__ Km,
    unsigned short* __restrict__ Mo) {
  __shared__ short Qs[128 * 72];
  __shared__ short Ks[64 * 72];
  int z = blockIdx.z, b = z >> 4, h = z & 15;
  int col0 = blockIdx.x << 6, row0 = blockIdx.y << 7;
  int tid = threadIdx.x;
  int lane = tid & 63, w = tid >> 6;
  int quad = lane >> 4, xn = lane & 15;
  const unsigned short* Qb = Q + (size_t)b * S_ * D_ + h * DK_;
  const unsigned short* Kb = Km + (size_t)b * S_ * D_ + h * DK_;
  for (int idx = tid; idx < 1024; idx += 256) {
    int r = idx >> 3, k8 = (idx & 7) << 3;
    uint4 v = *(const uint4*)&Qb[(size_t)(row0 + r) * D_ + k8];
    *(uint4*)&Qs[r * 72 + k8] = v;
  }
  for (int idx = tid; idx < 512; idx += 256) {
    int r = idx >> 3, k8 = (idx & 7) << 3;
    uint4 v = *(const uint4*)&Kb[(size_t)(col0 + r) * D_ + k8];
    *(uint4*)&Ks[r * 72 + k8] = v;
  }
  __syncthreads();
  floatx4 acc[2][4] = {};
#pragma unroll
  for (int ks = 0; ks < 2; ++ks) {
    bf16x8 af[2], bf[4];
#pragma unroll
    for (int rt = 0; rt < 2; ++rt)
      af[rt] = *(const bf16x8*)&Qs[(w * 32 + rt * 16 + xn) * 72 + ks * 32 + quad * 8];
#pragma unroll
    for (int ct = 0; ct < 4; ++ct)
      bf[ct] = *(const bf16x8*)&Ks[(ct * 16 + xn) * 72 + ks * 32 + quad * 8];
#pragma unroll
    for (int rt = 0; rt < 2; ++rt)
#pragma unroll
      for (int ct = 0; ct < 4; ++ct)
        acc[rt][ct] = __builtin_amdgcn_mfma_f32_16x16x32_bf16(
            af[rt], bf[ct], acc[rt][ct], 0, 0, 0);
  }
  unsigned short* Mb = Mo + (size_t)z * S_ * S_;
#pragma unroll
  for (int rt = 0; rt < 2; ++rt)
#pragma unroll
    for (int ct = 0; ct < 4; ++ct) {
      int t = col0 + ct * 16 + xn;
#pragma unroll
      for (int r = 0; r < 4; ++r) {
        int s = row0 + w * 32 + rt * 16 + quad * 4 + r;
        Mb[(size_t)s * S_ + t] = f2bf(acc[rt][ct][r]);
      }
    }
}

// ---------------------------------------------------------------------------
// repack16b: bf16 planar [b][16][Y][X] -> bf16 channel-fastest [b][y][x][16]
// ---------------------------------------------------------------------------
__global__ __launch_bounds__(256) void repack16b_kernel(
    const unsigned short* __restrict__ src, unsigned short* __restrict__ dst) {
  int x = (blockIdx.x << 8) + threadIdx.x;
  int y = blockIdx.y, b = blockIdx.z;
  const unsigned short* sp = src + ((size_t)b * 16 * S_ + y) * S_ + x;
  unsigned short out[16];
#pragma unroll
  for (int c = 0; c < 16; ++c) out[c] = sp[(size_t)c << 20];
  unsigned short* dp = dst + (((size_t)b * S_ + y) * S_ + x) * 16;
  unsigned wds[8];
#pragma unroll
  for (int i = 0; i < 8; ++i)
    wds[i] = (unsigned)out[2 * i] | ((unsigned)out[2 * i + 1] << 16);
  uint4 v0 = {wds[0], wds[1], wds[2], wds[3]};
  uint4 v1 = {wds[4], wds[5], wds[6], wds[7]};
  *(uint4*)dp = v0;
  *((uint4*)dp + 1) = v1;
}

// ---------------------------------------------------------------------------
// repack16: fp32 planar [b][16][Y][X] -> bf16 channel-fastest [b][y][x][16]
// ---------------------------------------------------------------------------
__global__ __launch_bounds__(256) void repack16_kernel(
    const float* __restrict__ src, unsigned short* __restrict__ dst) {
  int x = (blockIdx.x << 8) + threadIdx.x;
  int y = blockIdx.y, b = blockIdx.z;
  const float* sp = src + ((size_t)b * 16 * S_ + y) * S_ + x;
  unsigned short out[16];
#pragma unroll
  for (int c = 0; c < 16; ++c) out[c] = f2bf(sp[(size_t)c << 20]);
  unsigned short* dp = dst + (((size_t)b * S_ + y) * S_ + x) * 16;
  unsigned wds[8];
#pragma unroll
  for (int i = 0; i < 8; ++i)
    wds[i] = (unsigned)out[2 * i] | ((unsigned)out[2 * i + 1] << 16);
  uint4 v0 = {wds[0], wds[1], wds[2], wds[3]};
  uint4 v1 = {wds[4], wds[5], wds[6], wds[7]};
  *(uint4*)dp = v0;
  *((uint4*)dp + 1) = v1;
}

// ---------------------------------------------------------------------------
// conv_t (MFMA): 16ch -> 16ch 3x3 on prevT bf16 ch-fastest. Tile 64x8.
// grid (16, 128, 2). Wave handles 2 rows x 4 segs; K=32 tap-paired MFMAs.
// ---------------------------------------------------------------------------
__global__ __launch_bounds__(256) void conv_t_mfma_kernel(
    const unsigned short* __restrict__ prevT, const float* __restrict__ Wt,
    const float* __restrict__ bt, unsigned short* __restrict__ Mtbf) {
  __shared__ short Xs[10 * 66 * 24];
  int b = blockIdx.z;
  int x0 = blockIdx.x << 6, y0 = blockIdx.y << 3;
  int tid = threadIdx.x;
  int lane = tid & 63, w = tid >> 6;
  int quad = lane >> 4, xn = lane & 15;

  for (int idx = tid; idx < 1320; idx += 256) {
    int y = idx / 132;
    int r = idx - y * 132;
    int px = r >> 1, half = r & 1;
    int gy = y0 + y - 1, gx = x0 + px - 1;
    uint4 val = {0u, 0u, 0u, 0u};
    if ((unsigned)gy < (unsigned)S_ && (unsigned)gx < (unsigned)S_) {
      const unsigned short* sp =
          prevT + (((size_t)b * S_ + gy) * S_ + gx) * 16 + half * 8;
      val = *(const uint4*)sp;
    }
    *(uint4*)&Xs[(y * 66 + px) * 24 + half * 8] = val;
  }

  int m = xn;
  bf16x8 afr[5];
#pragma unroll
  for (int p = 0; p < 5; ++p) {
#pragma unroll
    for (int j = 0; j < 8; ++j) {
      int k = quad * 8 + j;
      int t = 2 * p + (k >> 4);
      float wv = 0.f;
      if (t < 9) wv = Wt[(m * 16 + (k & 15)) * 9 + t];
      afr[p][j] = (short)f2bf(wv);
    }
  }
  int tdy[5], tdx[5];
#pragma unroll
  for (int p = 0; p < 5; ++p) {
    int t = 2 * p + (quad >> 1);
    if (t > 8) t = 8;
    tdy[p] = t / 3;
    tdx[p] = t - tdy[p] * 3;
  }
  float btl[4];
#pragma unroll
  for (int r = 0; r < 4; ++r) btl[r] = bt[quad * 4 + r];

  __syncthreads();

#pragma unroll
  for (int ry = 0; ry < 2; ++ry) {
    int yl = w * 2 + ry;
    int y = y0 + yl;
#pragma unroll
    for (int seg = 0; seg < 4; ++seg) {
      floatx4 acc = {0.f, 0.f, 0.f, 0.f};
#pragma unroll
      for (int p = 0; p < 5; ++p) {
        const short* bp =
            &Xs[((yl + tdy[p]) * 66 + seg * 16 + xn + tdx[p]) * 24 + (quad & 1) * 8];
        bf16x8 bfr = *(const bf16x8*)bp;
        acc = __builtin_amdgcn_mfma_f32_16x16x32_bf16(afr[p], bfr, acc, 0, 0, 0);
      }
      ushort4 pk;
      pk.x = f2bf(acc[0] + btl[0]);
      pk.y = f2bf(acc[1] + btl[1]);
      pk.z = f2bf(acc[2] + btl[2]);
      pk.w = f2bf(acc[3] + btl[3]);
      int gx = x0 + seg * 16 + xn;
      *(ushort4*)&Mtbf[(((size_t)b * S_ + y) * S_ + gx) * 16 + quad * 4] = pk;
    }
  }
}

// ---------------------------------------------------------------------------
// FUSED conv_a + softmax + post-softmax mask — DIRECT-LOAD version (no LDS
// staging). The MFMA B-fragment for lane (quad,xn) is 8 consecutive channels
// at one pixel; Mbf/Mtbf are channel-fastest, so each fragment is ONE
// contiguous 16B global load (quad 0,1 = Mbf halves; 2,3 = Mtbf halves).
// Taps re-read through L1 (6.5 KB footprint/chunk). LDS = 512 B (reductions).
// Block = one (b, y) row; wave w owns px [w*32, w*32+32) of each 128-px chunk.
// grid (S, B). XCD-chunked y swizzle for halo L2 reuse.
// ---------------------------------------------------------------------------
__global__ __launch_bounds__(256) void conv_a_softmax_kernel(
    const unsigned short* __restrict__ Mbf, const unsigned short* __restrict__ Mtbf,
    const float* __restrict__ Wa, const float* __restrict__ ba,
    const int* __restrict__ mask,
    float* __restrict__ Aout, unsigned short* __restrict__ P0) {
  __shared__ float redm[4][4][4];
  __shared__ float reds[4][4][4];
  // bijective XCD swizzle: each of 8 XCDs gets a contiguous y-range
  int y = ((blockIdx.x & 7) << 7) + (blockIdx.x >> 3);
  int b = blockIdx.y;
  int tid = threadIdx.x;
  int lane = tid & 63, w = tid >> 6;
  int quad = lane >> 4, xn = lane & 15;

  // weight fragments: A rows = out-ch m = xn, k = quad*8+j = in-ch (0..31)
  bf16x8 afr[9];
#pragma unroll
  for (int t = 0; t < 9; ++t)
#pragma unroll
    for (int j = 0; j < 8; ++j)
      afr[t][j] = (short)f2bf(Wa[(xn * 32 + quad * 8 + j) * 9 + t]);
  float bal[4];
#pragma unroll
  for (int r = 0; r < 4; ++r) bal[r] = ba[quad * 4 + r];

  // per-lane B-fragment row pointers: quad selects tensor+half
  const unsigned short* tbase = (quad < 2) ? Mbf : Mtbf;
  int half = quad & 1;
  const unsigned short* rowb[3];
  int vy[3];
#pragma unroll
  for (int ry = 0; ry < 3; ++ry) {
    int gy = y + ry - 1;
    vy[ry] = ((unsigned)gy < (unsigned)S_) ? 1 : 0;
    int gyc = vy[ry] ? gy : 0;
    rowb[ry] = tbase + ((size_t)b * S_ + gyc) * (S_ * 16) + half * 8;
  }

  floatx4 acc[8][2] = {};
#pragma unroll
  for (int ci = 0; ci < 8; ++ci) {
#pragma unroll
    for (int sub = 0; sub < 2; ++sub) {
      int gx0 = (ci << 7) + (w << 5) + (sub << 4) + xn - 1;
      bf16x8 bv[9];
#pragma unroll
      for (int t = 0; t < 9; ++t) {
        const int dy = t / 3, dx = t - (t / 3) * 3;
        int gx = gx0 + dx;
        bf16x8 v = {0, 0, 0, 0, 0, 0, 0, 0};
        if (vy[dy] && (unsigned)gx < (unsigned)S_)
          v = *(const bf16x8*)(rowb[dy] + (size_t)gx * 16);
        bv[t] = v;
      }
      floatx4 a = acc[ci][sub];
#pragma unroll
      for (int t = 0; t < 9; ++t)
        a = __builtin_amdgcn_mfma_f32_16x16x32_bf16(afr[t], bv[t], a, 0, 0, 0);
      acc[ci][sub] = a;
    }
  }

  // bias + scale, per-channel row max (channel mo = quad*4+r)
  const float sc = 1.0f / 32.0f;
  float mx[4] = {-3.4e38f, -3.4e38f, -3.4e38f, -3.4e38f};
#pragma unroll
  for (int ci = 0; ci < 8; ++ci)
#pragma unroll
    for (int sub = 0; sub < 2; ++sub)
#pragma unroll
      for (int r = 0; r < 4; ++r) {
        float v = (acc[ci][sub][r] + bal[r]) * sc;
        acc[ci][sub][r] = v;
        mx[r] = fmaxf(mx[r], v);
      }
#pragma unroll
  for (int r = 0; r < 4; ++r) {
    mx[r] = fmaxf(mx[r], __shfl_xor(mx[r], 1));
    mx[r] = fmaxf(mx[r], __shfl_xor(mx[r], 2));
    mx[r] = fmaxf(mx[r], __shfl_xor(mx[r], 4));
    mx[r] = fmaxf(mx[r], __shfl_xor(mx[r], 8));
  }
  if (xn == 0) {
#pragma unroll
    for (int r = 0; r < 4; ++r) redm[w][quad][r] = mx[r];
  }
  __syncthreads();
  float fm[4];
#pragma unroll
  for (int r = 0; r < 4; ++r)
    fm[r] = fmaxf(fmaxf(redm[0][quad][r], redm[1][quad][r]),
                  fmaxf(redm[2][quad][r], redm[3][quad][r]));
  float sm[4] = {0.f, 0.f, 0.f, 0.f};
#pragma unroll
  for (int ci = 0; ci < 8; ++ci)
#pragma unroll
    for (int sub = 0; sub < 2; ++sub)
#pragma unroll
      for (int r = 0; r < 4; ++r) {
        float e = __expf(acc[ci][sub][r] - fm[r]);
        acc[ci][sub][r] = e;
        sm[r] += e;
      }
#pragma unroll
  for (int r = 0; r < 4; ++r) {
    sm[r] += __shfl_xor(sm[r], 1);
    sm[r] += __shfl_xor(sm[r], 2);
    sm[r] += __shfl_xor(sm[r], 4);
    sm[r] += __shfl_xor(sm[r], 8);
  }
  if (xn == 0) {
#pragma unroll
    for (int r = 0; r < 4; ++r) reds[w][quad][r] = sm[r];
  }
  __syncthreads();
  float inv[4];
#pragma unroll
  for (int r = 0; r < 4; ++r)
    inv[r] = 1.0f / (reds[0][quad][r] + reds[1][quad][r] +
                     reds[2][quad][r] + reds[3][quad][r]);

  const int* mb = mask + b * S_;
#pragma unroll
  for (int ci = 0; ci < 8; ++ci)
#pragma unroll
    for (int sub = 0; sub < 2; ++sub) {
      int gx = (ci << 7) + (w << 5) + (sub << 4) + xn;
      int mk = mb[gx];
#pragma unroll
      for (int r = 0; r < 4; ++r) {
        int mo = quad * 4 + r;
        size_t oidx = (((size_t)(b * 16 + mo)) << 20) + ((size_t)y << 10) + gx;
        float p = acc[ci][sub][r] * inv[r];
        Aout[oidx] = mk ? p : -1e9f;
        P0[oidx]  = mk ? f2bf(p) : (unsigned short)0;
      }
    }
}

// ---------------------------------------------------------------------------
// vtrans: V fp32 [b][t][h*64+d] -> Vt bf16 [(h*64+d)][b*1024+t] (per-head V^T)
// grid (S/64, B*H), 64x64 LDS transpose tiles.
// ---------------------------------------------------------------------------
__global__ __launch_bounds__(256) void vtrans_kernel(
    const float* __restrict__ V, unsigned short* __restrict__ Vt) {
  __shared__ unsigned short Ls[64][68];
  int z = blockIdx.y, b = z >> 4, h = z & 15;
  int t0 = blockIdx.x << 6;
  int tid = threadIdx.x;
  for (int idx = tid; idx < 1024; idx += 256) {
    int t = idx >> 4, d = (idx & 15) << 2;
    float4 v4 = *(const float4*)&V[((size_t)b * S_ + t0 + t) * D_ + h * 64 + d];
    ushort4 u;
    u.x = f2bf(v4.x); u.y = f2bf(v4.y); u.z = f2bf(v4.z); u.w = f2bf(v4.w);
    *(ushort4*)&Ls[t][d] = u;
  }
  __syncthreads();
  for (int idx = tid; idx < 1024; idx += 256) {
    int d = idx >> 4, tc = (idx & 15) << 2;
    ushort4 u;
    u.x = Ls[tc + 0][d]; u.y = Ls[tc + 1][d];
    u.z = Ls[tc + 2][d]; u.w = Ls[tc + 3][d];
    *(ushort4*)&Vt[((size_t)(h * 64 + d)) * 2048 + (size_t)b * S_ + t0 + tc] = u;
  }
}

// ---------------------------------------------------------------------------
// colsum stage 1: partial sums over 32-t chunks (deterministic, no atomics).
// grid (D/256, 32, B): block sums t in [32c, 32c+32) for 256 d's.
// cs_part[b][c][d]
// ---------------------------------------------------------------------------
__global__ __launch_bounds__(256) void colsum_part_kernel(
    const float* __restrict__ V, const int* __restrict__ mask,
    float* __restrict__ cs_part) {
  int b = blockIdx.z, c = blockIdx.y;
  int d = (blockIdx.x << 8) + threadIdx.x;
  const int* mb = mask + b * S_ + c * 32;
  const float* vp = V + ((size_t)b * S_ + c * 32) * D_ + d;
  float s = 0.f;
#pragma unroll
  for (int i = 0; i < 32; ++i) {
    float vv = vp[(size_t)i * D_];
    if (mb[i] == 0) s += vv;
  }
  cs_part[((size_t)b * 32 + c) * D_ + d] = s;
}

// colsum stage 2: fold 32 partials -> cs[b][d] (256 KB, L2-resident)
__global__ __launch_bounds__(256) void colsum_reduce_kernel(
    const float* __restrict__ cs_part, float* __restrict__ cs) {
  int i = (blockIdx.x << 8) + threadIdx.x;   // i = b*D + d
  int b = i >> 10, d = i & 1023;
  const float* pp = cs_part + ((size_t)b * 32) * D_ + d;
  float s = 0.f;
#pragma unroll
  for (int c = 0; c < 32; ++c) s += pp[(size_t)c * D_];
  cs[i] = s;
}

// corr[b][j] = -1e9 * sum_d cs[b][d] * Wo[j][d]   (fp32 GEMV)
__global__ __launch_bounds__(256) void corr_kernel(
    const float* __restrict__ cs, const float* __restrict__ Wo,
    float* __restrict__ corr) {
  int b = blockIdx.y;
  int j = (blockIdx.x << 6) + (threadIdx.x >> 2);
  int part = threadIdx.x & 3;
  const float* c = cs + b * D_ + part * 256;
  const float* wr = Wo + (size_t)j * D_ + part * 256;
  float s = 0.f;
  for (int i = 0; i < 256; i += 4) {
    float4 w4 = *(const float4*)&wr[i];
    float4 c4 = *(const float4*)&c[i];
    s = fmaf(w4.x, c4.x, s); s = fmaf(w4.y, c4.y, s);
    s = fmaf(w4.z, c4.z, s); s = fmaf(w4.w, c4.w, s);
  }
  s += __shfl_xor(s, 1);
  s += __shfl_xor(s, 2);
  if (part == 0) corr[b * D_ + j] = -1e9f * s;
}

// ---------------------------------------------------------------------------
// ctx (MFMA bf16): C[b,s,h*64+d] = sum_t P0[b,h,s,t] * Vt[h*64+d][b*1024+t]
// grid (S/64, B*H): 64 s-rows x 64 d-cols, BK=64, 4 waves of 16 rows each.
// ---------------------------------------------------------------------------
__global__ __launch_bounds__(256) void ctx_mfma_kernel(
    const unsigned short* __restrict__ P0, const unsigned short* __restrict__ Vt,
    unsigned short* __restrict__ Cbf) {
  __shared__ __attribute__((aligned(16))) short Ps[64 * 72];
  __shared__ __attribute__((aligned(16))) short Vs[64 * 72];
  int z = blockIdx.y, b = z >> 4, h = z & 15;
  int row0 = blockIdx.x << 6;
  int tid = threadIdx.x, lane = tid & 63, w = tid >> 6;
  int quad = lane >> 4, xn = lane & 15;
  const unsigned short* Pb = P0 + (size_t)z * S_ * S_ + (size_t)row0 * S_;
  const unsigned short* Vb = Vt + ((size_t)h * 64) * 2048 + (size_t)b * S_;
  floatx4 acc[4] = {};
  for (int k0 = 0; k0 < S_; k0 += 64) {
    for (int idx = tid; idx < 512; idx += 256) {
      int r = idx >> 3, c = (idx & 7) << 3;
      *(uint4*)&Ps[r * 72 + c] = *(const uint4*)&Pb[(size_t)r * S_ + k0 + c];
    }
    for (int idx = tid; idx < 512; idx += 256) {
      int r = idx >> 3, c = (idx & 7) << 3;
      *(uint4*)&Vs[r * 72 + c] = *(const uint4*)&Vb[(size_t)r * 2048 + k0 + c];
    }
    __syncthreads();
#pragma unroll
    for (int ks = 0; ks < 2; ++ks) {
      bf16x8 af = *(const bf16x8*)&Ps[(w * 16 + xn) * 72 + ks * 32 + quad * 8];
#pragma unroll
      for (int ct = 0; ct < 4; ++ct) {
        bf16x8 bfv = *(const bf16x8*)&Vs[(ct * 16 + xn) * 72 + ks * 32 + quad * 8];
        acc[ct] = __builtin_amdgcn_mfma_f32_16x16x32_bf16(af, bfv, acc[ct], 0, 0, 0);
      }
    }
    __syncthreads();
  }
  unsigned short* Co = Cbf + ((size_t)b * S_) * D_ + h * 64;
#pragma unroll
  for (int ct = 0; ct < 4; ++ct)
#pragma unroll
    for (int r = 0; r < 4; ++r) {
      int s = row0 + w * 16 + quad * 4 + r;
      Co[(size_t)s * D_ + ct * 16 + xn] = f2bf(acc[ct][r]);
    }
}

// ---------------------------------------------------------------------------
extern "C" void kernel_launch(void* const* d_in, const int* in_sizes, int n_in,
                              void* d_out, int out_size, void* d_ws, size_t ws_size,
                              hipStream_t stream) {
  const float* q    = (const float*)d_in[0];
  const float* k    = (const float*)d_in[1];
  const float* v    = (const float*)d_in[2];
  const int*   mask = (const int*)d_in[3];
  const float* prev = (const float*)d_in[4];
  const float* Wq   = (const float*)d_in[5];
  const float* Wk   = (const float*)d_in[6];
  const float* Wv   = (const float*)d_in[7];
  const float* Wo   = (const float*)d_in[8];
  const float* Wt   = (const float*)d_in[9];
  const float* bt   = (const float*)d_in[10];
  const float* Wa   = (const float*)d_in[11];
  const float* ba   = (const float*)d_in[12];

  float* out0 = (float*)d_out;          // [B,S,D]
  float* Aout = out0 + BSD;             // [B,H,S,S]

  // workspace carve (~222 MiB)
  char* wsp = (char*)d_ws;
  unsigned short* X1   = (unsigned short*)wsp; wsp += BSD * 2;             // 4 MB
  unsigned short* W1   = (unsigned short*)wsp; wsp += (size_t)D_ * D_ * 2; // 2 MB
  unsigned short* Qb   = (unsigned short*)wsp; wsp += BSD * 2;             // 4 MB
  unsigned short* Kb   = (unsigned short*)wsp; wsp += BSD * 2;             // 4 MB
  float* Vb            = (float*)wsp;          wsp += BSD * 4;             // 8 MB
  unsigned short* Vtb  = (unsigned short*)wsp; wsp += BSD * 2;             // 4 MB
  unsigned short* ctx1 = (unsigned short*)wsp; wsp += BSD * 2;             // 4 MB
  float* cs            = (float*)wsp;          wsp += (size_t)B_ * D_ * 4; // 8 KB
  float* corrb         = (float*)wsp;          wsp += (size_t)B_ * D_ * 4; // 8 KB
  float* cs_part       = (float*)wsp;          wsp += (size_t)B_ * 32 * D_ * 4; // 256 KB
  unsigned short* Mp   = (unsigned short*)wsp; wsp += BHSS * 2;            // 64 MiB
  unsigned short* Mbf  = (unsigned short*)wsp; wsp += BHSS * 2;            // 64 MiB
  unsigned short* Mtbf = (unsigned short*)wsp; wsp += BHSS * 2;            // 64 MiB
  unsigned short* prevT = Mp;  // alias: written after Mp consumed by repack16b
  unsigned short* P0    = Mp;  // alias: written after prevT consumed by conv_t

  dim3 blk(256);
  int n4x = (int)(BSD / 4);
  int n4w = (D_ * D_) / 4;
  dim3 gX((n4x + 255) / 256), gW((n4w + 255) / 256);
  dim3 gProjB(D_ / 64, (B_ * S_) / 64);

  // Q projection -> Qb (bf16)
  hipLaunchKernelGGL(cvt_bf16_kernel, gW, blk, 0, stream, Wq, W1, n4w);
  hipLaunchKernelGGL(cvt_bf16_kernel, gX, blk, 0, stream, q, X1, n4x);
  hipLaunchKernelGGL(gemm_bf16_nt_kernel, gProjB, blk, 0, stream, X1, W1,
                     (void*)Qb, D_, D_, 1, (const float*)nullptr);
  // K projection -> Kb (bf16)
  hipLaunchKernelGGL(cvt_bf16_kernel, gW, blk, 0, stream, Wk, W1, n4w);
  hipLaunchKernelGGL(cvt_bf16_kernel, gX, blk, 0, stream, k, X1, n4x);
  hipLaunchKernelGGL(gemm_bf16_nt_kernel, gProjB, blk, 0, stream, X1, W1,
                     (void*)Kb, D_, D_, 1, (const float*)nullptr);
  // V projection -> Vb (fp32: exact path for colsum correction)
  hipLaunchKernelGGL(cvt_bf16_kernel, gW, blk, 0, stream, Wv, W1, n4w);
  hipLaunchKernelGGL(cvt_bf16_kernel, gX, blk, 0, stream, v, X1, n4x);
  hipLaunchKernelGGL(gemm_bf16_nt_kernel, gProjB, blk, 0, stream, X1, W1,
                     (void*)Vb, D_, D_, 0, (const float*)nullptr);
  // Wo -> bf16 (W1 stays live until the final GEMM)
  hipLaunchKernelGGL(cvt_bf16_kernel, gW, blk, 0, stream, Wo, W1, n4w);

  // V^T bf16 per head; masked colsum of V (2-stage); corr = -1e9 * cs @ Wo^T
  hipLaunchKernelGGL(vtrans_kernel, dim3(S_ / 64, B_ * H_), blk, 0, stream, Vb, Vtb);
  hipLaunchKernelGGL(colsum_part_kernel, dim3(D_ / 256, 32, B_), blk, 0, stream,
                     Vb, mask, cs_part);
  hipLaunchKernelGGL(colsum_reduce_kernel, dim3((B_ * D_) / 256), blk, 0, stream,
                     cs_part, cs);
  hipLaunchKernelGGL(corr_kernel, dim3(D_ / 64, B_), blk, 0, stream, cs, Wo, corrb);

  // Scores (MFMA) -> Mp bf16 planar
  dim3 gSc(S_ / 64, S_ / 128, B_ * H_);
  hipLaunchKernelGGL(scores_mfma_kernel, gSc, blk, 0, stream, Qb, Kb, Mp);

  // Repack M -> ch-fastest (must precede prevT write into aliased region)
  dim3 gRep(S_ / 256, S_, B_);
  hipLaunchKernelGGL(repack16b_kernel, gRep, blk, 0, stream, Mp, Mbf);

  // Repack prev -> bf16 ch-fastest (overwrites Mp region)
  hipLaunchKernelGGL(repack16_kernel, gRep, blk, 0, stream, prev, prevT);

  // conv_t (MFMA) -> Mtbf
  dim3 gConv(S_ / 64, S_ / 8, B_);
  hipLaunchKernelGGL(conv_t_mfma_kernel, gConv, blk, 0, stream, prevT, Wt, bt, Mtbf);

  // FUSED conv_a + softmax + mask -> Aout (fp32 planar) + P0 (bf16 planar)
  // (P0 aliases Mp: prevT dead after conv_t)
  hipLaunchKernelGGL(conv_a_softmax_kernel, dim3(S_, B_), blk, 0, stream,
                     Mbf, Mtbf, Wa, ba, mask, Aout, P0);

  // ctx1 = P0 @ V (bf16 MFMA; -1e9 mass handled by corr)
  hipLaunchKernelGGL(ctx_mfma_kernel, dim3(S_ / 64, B_ * H_), blk, 0, stream,
                     P0, Vtb, ctx1);

  // out = ctx1 @ Wo^T (bf16 MFMA) + corr[b,:] broadcast (fp32 out)
  dim3 gProj(D_ / 64, (B_ * S_) / 64);
  hipLaunchKernelGGL(gemm_bf16_nt_kernel, gProj, blk, 0, stream, ctx1, W1,
                     (void*)out0, D_, D_, 0, (const float*)corrb);
}

// Round 8
// 658.958 us; speedup vs baseline: 1.0280x; 1.0280x over previous
//
#include <hip/hip_runtime.h>

// Problem constants
#define B_  2
#define S_  1024
#define H_  16
#define DK_ 64
#define D_  1024

static const size_t BSD  = (size_t)B_ * S_ * D_;        // 2,097,152
static const size_t BHSS = (size_t)B_ * H_ * S_ * S_;   // 33,554,432

typedef __attribute__((ext_vector_type(8))) short bf16x8;
typedef __attribute__((ext_vector_type(4))) float floatx4;

__device__ __forceinline__ unsigned short f2bf(float f) {
  unsigned u = __builtin_bit_cast(unsigned, f);
  unsigned r = (u + 0x7FFFu + ((u >> 16) & 1u)) >> 16;
  return (unsigned short)r;
}

// ---------------------------------------------------------------------------
// Flat fp32 -> bf16 convert (float4 per thread)
// ---------------------------------------------------------------------------
__global__ __launch_bounds__(256) void cvt_bf16_kernel(
    const float* __restrict__ src, unsigned short* __restrict__ dst, int n4) {
  int i = (blockIdx.x << 8) + threadIdx.x;
  if (i >= n4) return;
  float4 v = ((const float4*)src)[i];
  ushort4 o;
  o.x = f2bf(v.x); o.y = f2bf(v.y); o.z = f2bf(v.z); o.w = f2bf(v.w);
  ((ushort4*)dst)[i] = o;
}

// ---------------------------------------------------------------------------
// bf16 NT GEMM (MFMA): C[n][m] = sum_k A[n][k]*Bw[m][k], A,Bw bf16 row-major.
// 64x64 tile, BK=32, 256 thr = 4 waves, wave does 32x32 (2x2 of 16x16x32).
// bf16_out: 1 -> store bf16, 0 -> store fp32 (+ optional corr[b*1024+col]).
// grid (Mcols/64, N/64)
// ---------------------------------------------------------------------------
__global__ __launch_bounds__(256) void gemm_bf16_nt_kernel(
    const unsigned short* __restrict__ A, const unsigned short* __restrict__ Bw,
    void* __restrict__ Cout, int K, int Mcols, int bf16_out,
    const float* __restrict__ corr) {
  __shared__ short As[64 * 40];
  __shared__ short Bs[64 * 40];
  int tid = threadIdx.x;
  int lane = tid & 63, w = tid >> 6;
  int quad = lane >> 4, xn = lane & 15;
  int row0 = blockIdx.y << 6, col0 = blockIdx.x << 6;
  int rw = w & 1, cw = w >> 1;
  int srow = tid >> 2, sk = (tid & 3) << 3;   // staging: row 0..63, k-chunk
  const unsigned short* Ap = A + (size_t)(row0 + srow) * K + sk;
  const unsigned short* Bp = Bw + (size_t)(col0 + srow) * K + sk;
  floatx4 acc[2][2] = {};
  for (int k0 = 0; k0 < K; k0 += 32) {
    uint4 av = *(const uint4*)(Ap + k0);
    uint4 bv = *(const uint4*)(Bp + k0);
    *(uint4*)&As[srow * 40 + sk] = av;
    *(uint4*)&Bs[srow * 40 + sk] = bv;
    __syncthreads();
    bf16x8 af[2], bf[2];
#pragma unroll
    for (int rt = 0; rt < 2; ++rt)
      af[rt] = *(const bf16x8*)&As[(rw * 32 + rt * 16 + xn) * 40 + quad * 8];
#pragma unroll
    for (int ct = 0; ct < 2; ++ct)
      bf[ct] = *(const bf16x8*)&Bs[(cw * 32 + ct * 16 + xn) * 40 + quad * 8];
#pragma unroll
    for (int rt = 0; rt < 2; ++rt)
#pragma unroll
      for (int ct = 0; ct < 2; ++ct)
        acc[rt][ct] = __builtin_amdgcn_mfma_f32_16x16x32_bf16(
            af[rt], bf[ct], acc[rt][ct], 0, 0, 0);
    __syncthreads();
  }
#pragma unroll
  for (int rt = 0; rt < 2; ++rt)
#pragma unroll
    for (int ct = 0; ct < 2; ++ct) {
      int colg = col0 + cw * 32 + ct * 16 + xn;
#pragma unroll
      for (int r = 0; r < 4; ++r) {
        int rowg = row0 + rw * 32 + rt * 16 + quad * 4 + r;
        if (bf16_out)
          ((unsigned short*)Cout)[(size_t)rowg * Mcols + colg] = f2bf(acc[rt][ct][r]);
        else {
          float v = acc[rt][ct][r];
          if (corr) v += corr[((rowg >> 10) << 10) + colg];
          ((float*)Cout)[(size_t)rowg * Mcols + colg] = v;
        }
      }
    }
}

// ---------------------------------------------------------------------------
// Scores (MFMA): M[b,h,s,t] = sum_d Q[b,s,h,d]*K[b,t,h,d], Q/K bf16 [B,S,H*DK].
// Output bf16 planar [B,H,S,S]. Tile 128 (s) x 64 (t), K=64 single stage.
// grid (S/64, S/128, B*H), 256 thr = 4 waves, wave = 32 s-rows x 64 t-cols.
// ---------------------------------------------------------------------------
__global__ __launch_bounds__(256) void scores_mfma_kernel(
    const unsigned short* __restrict__ Q, const unsigned short* __restrict__ Km,
    unsigned short* __restrict__ Mo) {
  __shared__ short Qs[128 * 72];
  __shared__ short Ks[64 * 72];
  int z = blockIdx.z, b = z >> 4, h = z & 15;
  int col0 = blockIdx.x << 6, row0 = blockIdx.y << 7;
  int tid = threadIdx.x;
  int lane = tid & 63, w = tid >> 6;
  int quad = lane >> 4, xn = lane & 15;
  const unsigned short* Qb = Q + (size_t)b * S_ * D_ + h * DK_;
  const unsigned short* Kb = Km + (size_t)b * S_ * D_ + h * DK_;
  for (int idx = tid; idx < 1024; idx += 256) {
    int r = idx >> 3, k8 = (idx & 7) << 3;
    uint4 v = *(const uint4*)&Qb[(size_t)(row0 + r) * D_ + k8];
    *(uint4*)&Qs[r * 72 + k8] = v;
  }
  for (int idx = tid; idx < 512; idx += 256) {
    int r = idx >> 3, k8 = (idx & 7) << 3;
    uint4 v = *(const uint4*)&Kb[(size_t)(col0 + r) * D_ + k8];
    *(uint4*)&Ks[r * 72 + k8] = v;
  }
  __syncthreads();
  floatx4 acc[2][4] = {};
#pragma unroll
  for (int ks = 0; ks < 2; ++ks) {
    bf16x8 af[2], bf[4];
#pragma unroll
    for (int rt = 0; rt < 2; ++rt)
      af[rt] = *(const bf16x8*)&Qs[(w * 32 + rt * 16 + xn) * 72 + ks * 32 + quad * 8];
#pragma unroll
    for (int ct = 0; ct < 4; ++ct)
      bf[ct] = *(const bf16x8*)&Ks[(ct * 16 + xn) * 72 + ks * 32 + quad * 8];
#pragma unroll
    for (int rt = 0; rt < 2; ++rt)
#pragma unroll
      for (int ct = 0; ct < 4; ++ct)
        acc[rt][ct] = __builtin_amdgcn_mfma_f32_16x16x32_bf16(
            af[rt], bf[ct], acc[rt][ct], 0, 0, 0);
  }
  unsigned short* Mb = Mo + (size_t)z * S_ * S_;
#pragma unroll
  for (int rt = 0; rt < 2; ++rt)
#pragma unroll
    for (int ct = 0; ct < 4; ++ct) {
      int t = col0 + ct * 16 + xn;
#pragma unroll
      for (int r = 0; r < 4; ++r) {
        int s = row0 + w * 32 + rt * 16 + quad * 4 + r;
        Mb[(size_t)s * S_ + t] = f2bf(acc[rt][ct][r]);
      }
    }
}

// ---------------------------------------------------------------------------
// repack16b: bf16 planar [b][16][Y][X] -> bf16 channel-fastest [b][y][x][16]
// ---------------------------------------------------------------------------
__global__ __launch_bounds__(256) void repack16b_kernel(
    const unsigned short* __restrict__ src, unsigned short* __restrict__ dst) {
  int x = (blockIdx.x << 8) + threadIdx.x;
  int y = blockIdx.y, b = blockIdx.z;
  const unsigned short* sp = src + ((size_t)b * 16 * S_ + y) * S_ + x;
  unsigned short out[16];
#pragma unroll
  for (int c = 0; c < 16; ++c) out[c] = sp[(size_t)c << 20];
  unsigned short* dp = dst + (((size_t)b * S_ + y) * S_ + x) * 16;
  unsigned wds[8];
#pragma unroll
  for (int i = 0; i < 8; ++i)
    wds[i] = (unsigned)out[2 * i] | ((unsigned)out[2 * i + 1] << 16);
  uint4 v0 = {wds[0], wds[1], wds[2], wds[3]};
  uint4 v1 = {wds[4], wds[5], wds[6], wds[7]};
  *(uint4*)dp = v0;
  *((uint4*)dp + 1) = v1;
}

// ---------------------------------------------------------------------------
// repack16: fp32 planar [b][16][Y][X] -> bf16 channel-fastest [b][y][x][16]
// ---------------------------------------------------------------------------
__global__ __launch_bounds__(256) void repack16_kernel(
    const float* __restrict__ src, unsigned short* __restrict__ dst) {
  int x = (blockIdx.x << 8) + threadIdx.x;
  int y = blockIdx.y, b = blockIdx.z;
  const float* sp = src + ((size_t)b * 16 * S_ + y) * S_ + x;
  unsigned short out[16];
#pragma unroll
  for (int c = 0; c < 16; ++c) out[c] = f2bf(sp[(size_t)c << 20]);
  unsigned short* dp = dst + (((size_t)b * S_ + y) * S_ + x) * 16;
  unsigned wds[8];
#pragma unroll
  for (int i = 0; i < 8; ++i)
    wds[i] = (unsigned)out[2 * i] | ((unsigned)out[2 * i + 1] << 16);
  uint4 v0 = {wds[0], wds[1], wds[2], wds[3]};
  uint4 v1 = {wds[4], wds[5], wds[6], wds[7]};
  *(uint4*)dp = v0;
  *((uint4*)dp + 1) = v1;
}

// ---------------------------------------------------------------------------
// conv_t (MFMA): 16ch -> 16ch 3x3 on prevT bf16 ch-fastest. Tile 64x8.
// grid (16, 128, 2). Wave handles 2 rows x 4 segs; K=32 tap-paired MFMAs.
// ---------------------------------------------------------------------------
__global__ __launch_bounds__(256) void conv_t_mfma_kernel(
    const unsigned short* __restrict__ prevT, const float* __restrict__ Wt,
    const float* __restrict__ bt, unsigned short* __restrict__ Mtbf) {
  __shared__ short Xs[10 * 66 * 24];
  int b = blockIdx.z;
  int x0 = blockIdx.x << 6, y0 = blockIdx.y << 3;
  int tid = threadIdx.x;
  int lane = tid & 63, w = tid >> 6;
  int quad = lane >> 4, xn = lane & 15;

  for (int idx = tid; idx < 1320; idx += 256) {
    int y = idx / 132;
    int r = idx - y * 132;
    int px = r >> 1, half = r & 1;
    int gy = y0 + y - 1, gx = x0 + px - 1;
    uint4 val = {0u, 0u, 0u, 0u};
    if ((unsigned)gy < (unsigned)S_ && (unsigned)gx < (unsigned)S_) {
      const unsigned short* sp =
          prevT + (((size_t)b * S_ + gy) * S_ + gx) * 16 + half * 8;
      val = *(const uint4*)sp;
    }
    *(uint4*)&Xs[(y * 66 + px) * 24 + half * 8] = val;
  }

  int m = xn;
  bf16x8 afr[5];
#pragma unroll
  for (int p = 0; p < 5; ++p) {
#pragma unroll
    for (int j = 0; j < 8; ++j) {
      int k = quad * 8 + j;
      int t = 2 * p + (k >> 4);
      float wv = 0.f;
      if (t < 9) wv = Wt[(m * 16 + (k & 15)) * 9 + t];
      afr[p][j] = (short)f2bf(wv);
    }
  }
  int tdy[5], tdx[5];
#pragma unroll
  for (int p = 0; p < 5; ++p) {
    int t = 2 * p + (quad >> 1);
    if (t > 8) t = 8;
    tdy[p] = t / 3;
    tdx[p] = t - tdy[p] * 3;
  }
  float btl[4];
#pragma unroll
  for (int r = 0; r < 4; ++r) btl[r] = bt[quad * 4 + r];

  __syncthreads();

#pragma unroll
  for (int ry = 0; ry < 2; ++ry) {
    int yl = w * 2 + ry;
    int y = y0 + yl;
#pragma unroll
    for (int seg = 0; seg < 4; ++seg) {
      floatx4 acc = {0.f, 0.f, 0.f, 0.f};
#pragma unroll
      for (int p = 0; p < 5; ++p) {
        const short* bp =
            &Xs[((yl + tdy[p]) * 66 + seg * 16 + xn + tdx[p]) * 24 + (quad & 1) * 8];
        bf16x8 bfr = *(const bf16x8*)bp;
        acc = __builtin_amdgcn_mfma_f32_16x16x32_bf16(afr[p], bfr, acc, 0, 0, 0);
      }
      ushort4 pk;
      pk.x = f2bf(acc[0] + btl[0]);
      pk.y = f2bf(acc[1] + btl[1]);
      pk.z = f2bf(acc[2] + btl[2]);
      pk.w = f2bf(acc[3] + btl[3]);
      int gx = x0 + seg * 16 + xn;
      *(ushort4*)&Mtbf[(((size_t)b * S_ + y) * S_ + gx) * 16 + quad * 4] = pk;
    }
  }
}

// ---------------------------------------------------------------------------
// FUSED conv_a + softmax + post-softmax mask — wave-autonomous, conflict-free
// LDS layout [3 rows][4 ch-groups][34 px][8 ch] (16B px-stride). Prefetch
// window = 4 slots in registers (occupancy-friendly); remaining 3 slots
// loaded just-in-time per chunk. __launch_bounds__(256,3) pins <=170 regs
// -> 3 waves/SIMD.
// Block = one (b, y) row; wave w owns px [w*32, w*32+32) of each 128-px chunk.
// grid (S, B). XCD-chunked y swizzle for halo L2 reuse.
// ---------------------------------------------------------------------------
__global__ __launch_bounds__(256, 3) void conv_a_softmax_kernel(
    const unsigned short* __restrict__ Mbf, const unsigned short* __restrict__ Mtbf,
    const float* __restrict__ Wa, const float* __restrict__ ba,
    const int* __restrict__ mask,
    float* __restrict__ Aout, unsigned short* __restrict__ P0) {
  // per-wave LDS slice: [3][4][34][8] shorts = 3264 shorts = 6528 B
  __shared__ __attribute__((aligned(16))) short Xs[4 * 3264];
  __shared__ float redm[4][4][4];
  __shared__ float reds[4][4][4];
  // bijective XCD swizzle: each of 8 XCDs gets a contiguous y-range
  int y = ((blockIdx.x & 7) << 7) + (blockIdx.x >> 3);
  int b = blockIdx.y;
  int tid = threadIdx.x;
  int lane = tid & 63, w = tid >> 6;
  int quad = lane >> 4, xn = lane & 15;

  // weight fragments: A rows = out-ch m = xn, k = quad*8+j = in-ch (0..31)
  bf16x8 afr[9];
#pragma unroll
  for (int t = 0; t < 9; ++t)
#pragma unroll
    for (int j = 0; j < 8; ++j)
      afr[t][j] = (short)f2bf(Wa[(xn * 32 + quad * 8 + j) * 9 + t]);
  float bal[4];
#pragma unroll
  for (int r = 0; r < 4; ++r) bal[r] = ba[quad * 4 + r];

  short* XsW = &Xs[w * 3264];

  // per-lane slot table: 408 slots (3 rows x 34 px x 4 parts) over 64 lanes,
  // 7 iters (iter 6: lanes 0..23 only). Slot s -> ry = s/136, px = (s%136)>>2,
  // part = s&3. part 0,1 = Mbf halves; 2,3 = Mtbf halves.
  const unsigned short* s_base[7];
  int s_pxo[7], s_lds[7], s_vy[7];
#pragma unroll
  for (int it = 0; it < 7; ++it) {
    int s = it * 64 + lane;
    int ry = (s >= 272) ? 2 : ((s >= 136) ? 1 : 0);
    int rem = s - ry * 136;
    int px = rem >> 2, part = rem & 3;
    int gy = y + ry - 1;
    int vyy = ((unsigned)gy < (unsigned)S_) ? 1 : 0;
    int gyc = vyy ? gy : 0;
    const unsigned short* base = (part < 2) ? Mbf : Mtbf;
    s_base[it] = base + ((size_t)b * S_ + gyc) * (S_ * 16) + (part & 1) * 8
                 + (size_t)(px - 1) * 16;
    s_vy[it]  = vyy;
    s_pxo[it] = px - 1;
    s_lds[it] = ((ry * 4 + part) * 34 + px) * 8;
  }

  // prologue: prefetch chunk 0, slots 0..3
  uint4 ld[4];
  {
    int x0 = (w << 5);
#pragma unroll
    for (int it = 0; it < 4; ++it) {
      uint4 val = {0u, 0u, 0u, 0u};
      int gx = x0 + s_pxo[it];
      if (s_vy[it] && (unsigned)gx < (unsigned)S_)
        val = *(const uint4*)(s_base[it] + (size_t)x0 * 16);
      ld[it] = val;
    }
  }

  floatx4 acc[8][2] = {};
#pragma unroll
  for (int ci = 0; ci < 8; ++ci) {
    int x0 = (ci << 7) + (w << 5);
    // write prefetched slots 0..3 -> LDS
#pragma unroll
    for (int it = 0; it < 4; ++it)
      *(uint4*)&XsW[s_lds[it]] = ld[it];
    // jit: load + write slots 4..6 for this chunk
    {
      uint4 jv[3];
#pragma unroll
      for (int j = 0; j < 3; ++j) {
        int it = 4 + j;
        uint4 val = {0u, 0u, 0u, 0u};
        if (it < 6 || lane < 24) {
          int gx = x0 + s_pxo[it];
          if (s_vy[it] && (unsigned)gx < (unsigned)S_)
            val = *(const uint4*)(s_base[it] + (size_t)x0 * 16);
        }
        jv[j] = val;
      }
#pragma unroll
      for (int j = 0; j < 3; ++j) {
        int it = 4 + j;
        if (it < 6 || lane < 24)
          *(uint4*)&XsW[s_lds[it]] = jv[j];
      }
    }
    __builtin_amdgcn_wave_barrier();   // fence: writes before reads
    // prefetch next chunk's slots 0..3 (latency hides under MFMA below)
    if (ci < 7) {
      int x0n = ((ci + 1) << 7) + (w << 5);
#pragma unroll
      for (int it = 0; it < 4; ++it) {
        uint4 val = {0u, 0u, 0u, 0u};
        int gx = x0n + s_pxo[it];
        if (s_vy[it] && (unsigned)gx < (unsigned)S_)
          val = *(const uint4*)(s_base[it] + (size_t)x0n * 16);
        ld[it] = val;
      }
    }
    // MFMA on the wave's 32 px (conflict-free 16B-stride reads)
#pragma unroll
    for (int sub = 0; sub < 2; ++sub) {
      int sp = (sub << 4) + xn;
      floatx4 a = acc[ci][sub];
#pragma unroll
      for (int t = 0; t < 9; ++t) {
        const int dy = t / 3, dx = t - (t / 3) * 3;
        bf16x8 bfr = *(const bf16x8*)&XsW[((dy * 4 + quad) * 34 + sp + dx) * 8];
        a = __builtin_amdgcn_mfma_f32_16x16x32_bf16(afr[t], bfr, a, 0, 0, 0);
      }
      acc[ci][sub] = a;
    }
    __builtin_amdgcn_wave_barrier();   // fence: reads before next chunk's writes
  }

  // bias + scale, per-channel row max (channel mo = quad*4+r)
  const float sc = 1.0f / 32.0f;
  float mx[4] = {-3.4e38f, -3.4e38f, -3.4e38f, -3.4e38f};
#pragma unroll
  for (int ci = 0; ci < 8; ++ci)
#pragma unroll
    for (int sub = 0; sub < 2; ++sub)
#pragma unroll
      for (int r = 0; r < 4; ++r) {
        float v = (acc[ci][sub][r] + bal[r]) * sc;
        acc[ci][sub][r] = v;
        mx[r] = fmaxf(mx[r], v);
      }
#pragma unroll
  for (int r = 0; r < 4; ++r) {
    mx[r] = fmaxf(mx[r], __shfl_xor(mx[r], 1));
    mx[r] = fmaxf(mx[r], __shfl_xor(mx[r], 2));
    mx[r] = fmaxf(mx[r], __shfl_xor(mx[r], 4));
    mx[r] = fmaxf(mx[r], __shfl_xor(mx[r], 8));
  }
  if (xn == 0) {
#pragma unroll
    for (int r = 0; r < 4; ++r) redm[w][quad][r] = mx[r];
  }
  __syncthreads();
  float fm[4];
#pragma unroll
  for (int r = 0; r < 4; ++r)
    fm[r] = fmaxf(fmaxf(redm[0][quad][r], redm[1][quad][r]),
                  fmaxf(redm[2][quad][r], redm[3][quad][r]));
  float sm[4] = {0.f, 0.f, 0.f, 0.f};
#pragma unroll
  for (int ci = 0; ci < 8; ++ci)
#pragma unroll
    for (int sub = 0; sub < 2; ++sub)
#pragma unroll
      for (int r = 0; r < 4; ++r) {
        float e = __expf(acc[ci][sub][r] - fm[r]);
        acc[ci][sub][r] = e;
        sm[r] += e;
      }
#pragma unroll
  for (int r = 0; r < 4; ++r) {
    sm[r] += __shfl_xor(sm[r], 1);
    sm[r] += __shfl_xor(sm[r], 2);
    sm[r] += __shfl_xor(sm[r], 4);
    sm[r] += __shfl_xor(sm[r], 8);
  }
  if (xn == 0) {
#pragma unroll
    for (int r = 0; r < 4; ++r) reds[w][quad][r] = sm[r];
  }
  __syncthreads();
  float inv[4];
#pragma unroll
  for (int r = 0; r < 4; ++r)
    inv[r] = 1.0f / (reds[0][quad][r] + reds[1][quad][r] +
                     reds[2][quad][r] + reds[3][quad][r]);

  const int* mb = mask + b * S_;
#pragma unroll
  for (int ci = 0; ci < 8; ++ci)
#pragma unroll
    for (int sub = 0; sub < 2; ++sub) {
      int gx = (ci << 7) + (w << 5) + (sub << 4) + xn;
      int mk = mb[gx];
#pragma unroll
      for (int r = 0; r < 4; ++r) {
        int mo = quad * 4 + r;
        size_t oidx = (((size_t)(b * 16 + mo)) << 20) + ((size_t)y << 10) + gx;
        float p = acc[ci][sub][r] * inv[r];
        Aout[oidx] = mk ? p : -1e9f;
        P0[oidx]  = mk ? f2bf(p) : (unsigned short)0;
      }
    }
}

// ---------------------------------------------------------------------------
// vtrans: V fp32 [b][t][h*64+d] -> Vt bf16 [(h*64+d)][b*1024+t] (per-head V^T)
// grid (S/64, B*H), 64x64 LDS transpose tiles.
// ---------------------------------------------------------------------------
__global__ __launch_bounds__(256) void vtrans_kernel(
    const float* __restrict__ V, unsigned short* __restrict__ Vt) {
  __shared__ unsigned short Ls[64][68];
  int z = blockIdx.y, b = z >> 4, h = z & 15;
  int t0 = blockIdx.x << 6;
  int tid = threadIdx.x;
  for (int idx = tid; idx < 1024; idx += 256) {
    int t = idx >> 4, d = (idx & 15) << 2;
    float4 v4 = *(const float4*)&V[((size_t)b * S_ + t0 + t) * D_ + h * 64 + d];
    ushort4 u;
    u.x = f2bf(v4.x); u.y = f2bf(v4.y); u.z = f2bf(v4.z); u.w = f2bf(v4.w);
    *(ushort4*)&Ls[t][d] = u;
  }
  __syncthreads();
  for (int idx = tid; idx < 1024; idx += 256) {
    int d = idx >> 4, tc = (idx & 15) << 2;
    ushort4 u;
    u.x = Ls[tc + 0][d]; u.y = Ls[tc + 1][d];
    u.z = Ls[tc + 2][d]; u.w = Ls[tc + 3][d];
    *(ushort4*)&Vt[((size_t)(h * 64 + d)) * 2048 + (size_t)b * S_ + t0 + tc] = u;
  }
}

// ---------------------------------------------------------------------------
// colsum stage 1: partial sums over 32-t chunks (deterministic, no atomics).
// grid (D/256, 32, B): block sums t in [32c, 32c+32) for 256 d's.
// cs_part[b][c][d]
// ---------------------------------------------------------------------------
__global__ __launch_bounds__(256) void colsum_part_kernel(
    const float* __restrict__ V, const int* __restrict__ mask,
    float* __restrict__ cs_part) {
  int b = blockIdx.z, c = blockIdx.y;
  int d = (blockIdx.x << 8) + threadIdx.x;
  const int* mb = mask + b * S_ + c * 32;
  const float* vp = V + ((size_t)b * S_ + c * 32) * D_ + d;
  float s = 0.f;
#pragma unroll
  for (int i = 0; i < 32; ++i) {
    float vv = vp[(size_t)i * D_];
    if (mb[i] == 0) s += vv;
  }
  cs_part[((size_t)b * 32 + c) * D_ + d] = s;
}

// colsum stage 2: fold 32 partials -> cs[b][d] (256 KB, L2-resident)
__global__ __launch_bounds__(256) void colsum_reduce_kernel(
    const float* __restrict__ cs_part, float* __restrict__ cs) {
  int i = (blockIdx.x << 8) + threadIdx.x;   // i = b*D + d
  int b = i >> 10, d = i & 1023;
  const float* pp = cs_part + ((size_t)b * 32) * D_ + d;
  float s = 0.f;
#pragma unroll
  for (int c = 0; c < 32; ++c) s += pp[(size_t)c * D_];
  cs[i] = s;
}

// corr[b][j] = -1e9 * sum_d cs[b][d] * Wo[j][d]   (fp32 GEMV)
__global__ __launch_bounds__(256) void corr_kernel(
    const float* __restrict__ cs, const float* __restrict__ Wo,
    float* __restrict__ corr) {
  int b = blockIdx.y;
  int j = (blockIdx.x << 6) + (threadIdx.x >> 2);
  int part = threadIdx.x & 3;
  const float* c = cs + b * D_ + part * 256;
  const float* wr = Wo + (size_t)j * D_ + part * 256;
  float s = 0.f;
  for (int i = 0; i < 256; i += 4) {
    float4 w4 = *(const float4*)&wr[i];
    float4 c4 = *(const float4*)&c[i];
    s = fmaf(w4.x, c4.x, s); s = fmaf(w4.y, c4.y, s);
    s = fmaf(w4.z, c4.z, s); s = fmaf(w4.w, c4.w, s);
  }
  s += __shfl_xor(s, 1);
  s += __shfl_xor(s, 2);
  if (part == 0) corr[b * D_ + j] = -1e9f * s;
}

// ---------------------------------------------------------------------------
// ctx (MFMA bf16): C[b,s,h*64+d] = sum_t P0[b,h,s,t] * Vt[h*64+d][b*1024+t]
// grid (S/64, B*H): 64 s-rows x 64 d-cols, BK=64, 4 waves of 16 rows each.
// ---------------------------------------------------------------------------
__global__ __launch_bounds__(256) void ctx_mfma_kernel(
    const unsigned short* __restrict__ P0, const unsigned short* __restrict__ Vt,
    unsigned short* __restrict__ Cbf) {
  __shared__ __attribute__((aligned(16))) short Ps[64 * 72];
  __shared__ __attribute__((aligned(16))) short Vs[64 * 72];
  int z = blockIdx.y, b = z >> 4, h = z & 15;
  int row0 = blockIdx.x << 6;
  int tid = threadIdx.x, lane = tid & 63, w = tid >> 6;
  int quad = lane >> 4, xn = lane & 15;
  const unsigned short* Pb = P0 + (size_t)z * S_ * S_ + (size_t)row0 * S_;
  const unsigned short* Vb = Vt + ((size_t)h * 64) * 2048 + (size_t)b * S_;
  floatx4 acc[4] = {};
  for (int k0 = 0; k0 < S_; k0 += 64) {
    for (int idx = tid; idx < 512; idx += 256) {
      int r = idx >> 3, c = (idx & 7) << 3;
      *(uint4*)&Ps[r * 72 + c] = *(const uint4*)&Pb[(size_t)r * S_ + k0 + c];
    }
    for (int idx = tid; idx < 512; idx += 256) {
      int r = idx >> 3, c = (idx & 7) << 3;
      *(uint4*)&Vs[r * 72 + c] = *(const uint4*)&Vb[(size_t)r * 2048 + k0 + c];
    }
    __syncthreads();
#pragma unroll
    for (int ks = 0; ks < 2; ++ks) {
      bf16x8 af = *(const bf16x8*)&Ps[(w * 16 + xn) * 72 + ks * 32 + quad * 8];
#pragma unroll
      for (int ct = 0; ct < 4; ++ct) {
        bf16x8 bfv = *(const bf16x8*)&Vs[(ct * 16 + xn) * 72 + ks * 32 + quad * 8];
        acc[ct] = __builtin_amdgcn_mfma_f32_16x16x32_bf16(af, bfv, acc[ct], 0, 0, 0);
      }
    }
    __syncthreads();
  }
  unsigned short* Co = Cbf + ((size_t)b * S_) * D_ + h * 64;
#pragma unroll
  for (int ct = 0; ct < 4; ++ct)
#pragma unroll
    for (int r = 0; r < 4; ++r) {
      int s = row0 + w * 16 + quad * 4 + r;
      Co[(size_t)s * D_ + ct * 16 + xn] = f2bf(acc[ct][r]);
    }
}

// ---------------------------------------------------------------------------
extern "C" void kernel_launch(void* const* d_in, const int* in_sizes, int n_in,
                              void* d_out, int out_size, void* d_ws, size_t ws_size,
                              hipStream_t stream) {
  const float* q    = (const float*)d_in[0];
  const float* k    = (const float*)d_in[1];
  const float* v    = (const float*)d_in[2];
  const int*   mask = (const int*)d_in[3];
  const float* prev = (const float*)d_in[4];
  const float* Wq   = (const float*)d_in[5];
  const float* Wk   = (const float*)d_in[6];
  const float* Wv   = (const float*)d_in[7];
  const float* Wo   = (const float*)d_in[8];
  const float* Wt   = (const float*)d_in[9];
  const float* bt   = (const float*)d_in[10];
  const float* Wa   = (const float*)d_in[11];
  const float* ba   = (const float*)d_in[12];

  float* out0 = (float*)d_out;          // [B,S,D]
  float* Aout = out0 + BSD;             // [B,H,S,S]

  // workspace carve (~222 MiB)
  char* wsp = (char*)d_ws;
  unsigned short* X1   = (unsigned short*)wsp; wsp += BSD * 2;             // 4 MB
  unsigned short* W1   = (unsigned short*)wsp; wsp += (size_t)D_ * D_ * 2; // 2 MB
  unsigned short* Qb   = (unsigned short*)wsp; wsp += BSD * 2;             // 4 MB
  unsigned short* Kb   = (unsigned short*)wsp; wsp += BSD * 2;             // 4 MB
  float* Vb            = (float*)wsp;          wsp += BSD * 4;             // 8 MB
  unsigned short* Vtb  = (unsigned short*)wsp; wsp += BSD * 2;             // 4 MB
  unsigned short* ctx1 = (unsigned short*)wsp; wsp += BSD * 2;             // 4 MB
  float* cs            = (float*)wsp;          wsp += (size_t)B_ * D_ * 4; // 8 KB
  float* corrb         = (float*)wsp;          wsp += (size_t)B_ * D_ * 4; // 8 KB
  float* cs_part       = (float*)wsp;          wsp += (size_t)B_ * 32 * D_ * 4; // 256 KB
  unsigned short* Mp   = (unsigned short*)wsp; wsp += BHSS * 2;            // 64 MiB
  unsigned short* Mbf  = (unsigned short*)wsp; wsp += BHSS * 2;            // 64 MiB
  unsigned short* Mtbf = (unsigned short*)wsp; wsp += BHSS * 2;            // 64 MiB
  unsigned short* prevT = Mp;  // alias: written after Mp consumed by repack16b
  unsigned short* P0    = Mp;  // alias: written after prevT consumed by conv_t

  dim3 blk(256);
  int n4x = (int)(BSD / 4);
  int n4w = (D_ * D_) / 4;
  dim3 gX((n4x + 255) / 256), gW((n4w + 255) / 256);
  dim3 gProjB(D_ / 64, (B_ * S_) / 64);

  // Q projection -> Qb (bf16)
  hipLaunchKernelGGL(cvt_bf16_kernel, gW, blk, 0, stream, Wq, W1, n4w);
  hipLaunchKernelGGL(cvt_bf16_kernel, gX, blk, 0, stream, q, X1, n4x);
  hipLaunchKernelGGL(gemm_bf16_nt_kernel, gProjB, blk, 0, stream, X1, W1,
                     (void*)Qb, D_, D_, 1, (const float*)nullptr);
  // K projection -> Kb (bf16)
  hipLaunchKernelGGL(cvt_bf16_kernel, gW, blk, 0, stream, Wk, W1, n4w);
  hipLaunchKernelGGL(cvt_bf16_kernel, gX, blk, 0, stream, k, X1, n4x);
  hipLaunchKernelGGL(gemm_bf16_nt_kernel, gProjB, blk, 0, stream, X1, W1,
                     (void*)Kb, D_, D_, 1, (const float*)nullptr);
  // V projection -> Vb (fp32: exact path for colsum correction)
  hipLaunchKernelGGL(cvt_bf16_kernel, gW, blk, 0, stream, Wv, W1, n4w);
  hipLaunchKernelGGL(cvt_bf16_kernel, gX, blk, 0, stream, v, X1, n4x);
  hipLaunchKernelGGL(gemm_bf16_nt_kernel, gProjB, blk, 0, stream, X1, W1,
                     (void*)Vb, D_, D_, 0, (const float*)nullptr);
  // Wo -> bf16 (W1 stays live until the final GEMM)
  hipLaunchKernelGGL(cvt_bf16_kernel, gW, blk, 0, stream, Wo, W1, n4w);

  // V^T bf16 per head; masked colsum of V (2-stage); corr = -1e9 * cs @ Wo^T
  hipLaunchKernelGGL(vtrans_kernel, dim3(S_ / 64, B_ * H_), blk, 0, stream, Vb, Vtb);
  hipLaunchKernelGGL(colsum_part_kernel, dim3(D_ / 256, 32, B_), blk, 0, stream,
                     Vb, mask, cs_part);
  hipLaunchKernelGGL(colsum_reduce_kernel, dim3((B_ * D_) / 256), blk, 0, stream,
                     cs_part, cs);
  hipLaunchKernelGGL(corr_kernel, dim3(D_ / 64, B_), blk, 0, stream, cs, Wo, corrb);

  // Scores (MFMA) -> Mp bf16 planar
  dim3 gSc(S_ / 64, S_ / 128, B_ * H_);
  hipLaunchKernelGGL(scores_mfma_kernel, gSc, blk, 0, stream, Qb, Kb, Mp);

  // Repack M -> ch-fastest (must precede prevT write into aliased region)
  dim3 gRep(S_ / 256, S_, B_);
  hipLaunchKernelGGL(repack16b_kernel, gRep, blk, 0, stream, Mp, Mbf);

  // Repack prev -> bf16 ch-fastest (overwrites Mp region)
  hipLaunchKernelGGL(repack16_kernel, gRep, blk, 0, stream, prev, prevT);

  // conv_t (MFMA) -> Mtbf
  dim3 gConv(S_ / 64, S_ / 8, B_);
  hipLaunchKernelGGL(conv_t_mfma_kernel, gConv, blk, 0, stream, prevT, Wt, bt, Mtbf);

  // FUSED conv_a + softmax + mask -> Aout (fp32 planar) + P0 (bf16 planar)
  // (P0 aliases Mp: prevT dead after conv_t)
  hipLaunchKernelGGL(conv_a_softmax_kernel, dim3(S_, B_), blk, 0, stream,
                     Mbf, Mtbf, Wa, ba, mask, Aout, P0);

  // ctx1 = P0 @ V (bf16 MFMA; -1e9 mass handled by corr)
  hipLaunchKernelGGL(ctx_mfma_kernel, dim3(S_ / 64, B_ * H_), blk, 0, stream,
                     P0, Vtb, ctx1);

  // out = ctx1 @ Wo^T (bf16 MFMA) + corr[b,:] broadcast (fp32 out)
  dim3 gProj(D_ / 64, (B_ * S_) / 64);
  hipLaunchKernelGGL(gemm_bf16_nt_kernel, gProj, blk, 0, stream, ctx1, W1,
                     (void*)out0, D_, D_, 0, (const float*)corrb);
}